// Round 2
// 437.456 us; speedup vs baseline: 1.0031x; 1.0031x over previous
//
#include <hip/hip_runtime.h>
#include <math.h>

#define N_NODES 50000
#define N_EDGES 800000
#define SCAN_BLK 2048   // elements per scan block (256 threads x 8)
#define LDS_STRIDE 264  // 256 shorts + 8 pad (bank spread)

using short8  = __attribute__((ext_vector_type(8))) short;
using floatx4 = __attribute__((ext_vector_type(4))) float;
using ushortx8 = __attribute__((ext_vector_type(8))) unsigned short;
using uintx4  = __attribute__((ext_vector_type(4))) unsigned;
using uintx2  = __attribute__((ext_vector_type(2))) unsigned;

__device__ inline unsigned short f2bf(float f) {
  unsigned u = __float_as_uint(f);
  u += 0x7fff + ((u >> 16) & 1);   // round-to-nearest-even
  return (unsigned short)(u >> 16);
}

__device__ inline float sigmoidf(float x) { return 1.0f / (1.0f + __expf(-x)); }

// ---------------- prep: edge count + weight pack ----------------
__global__ void prep_kernel(const int* __restrict__ rows, int* __restrict__ counts, int E, int cntB,
                            const float* __restrict__ W1, const float* __restrict__ G1,
                            const float* __restrict__ W2, const float* __restrict__ G2,
                            unsigned short* __restrict__ Wp1, unsigned short* __restrict__ Gp1,
                            unsigned short* __restrict__ Wp2, unsigned short* __restrict__ Gp2) {
  int b = blockIdx.x;
  if (b < cntB) {
    int e = b * 256 + threadIdx.x;
    if (e < E) atomicAdd(&counts[rows[e]], 1);
  } else {
    int idx = (b - cntB) * 256 + threadIdx.x;
    if (idx < 65536) {
      int m = idx >> 8, k = idx & 255;
      Wp1[idx] = f2bf(W1[k * 256 + m]);
    } else if (idx < 131072) {
      int t = idx - 65536; int m = t >> 8, k = t & 255;
      Gp1[t] = f2bf(G1[k * 256 + m]);
    } else if (idx < 163840) {
      int t = idx - 131072; int m = t >> 8, k = t & 255;
      Wp2[t] = f2bf(W2[k * 128 + m]);
    } else {
      int t = idx - 163840; int m = t >> 8, k = t & 255;
      Gp2[t] = f2bf(G2[k * 128 + m]);
    }
  }
}

// ---------------- single-kernel exclusive scan ----------------
__global__ void scan_kernel(const int* __restrict__ counts, int* __restrict__ row_ptr,
                            int* __restrict__ cursor, int N, int E) {
  int tid = threadIdx.x, lane = tid & 63, wv = tid >> 6;
  __shared__ int wpart[4], wsum[4];

  int limit4 = (blockIdx.x * SCAN_BLK) >> 2;
  const int4* c4 = (const int4*)counts;
  int s = 0;
  for (int i = tid; i < limit4; i += 256) {
    int4 v = c4[i];
    s += v.x + v.y + v.z + v.w;
  }
#pragma unroll
  for (int d = 32; d > 0; d >>= 1) s += __shfl_down(s, d, 64);
  if (lane == 0) wpart[wv] = s;
  __syncthreads();
  int blk_off = wpart[0] + wpart[1] + wpart[2] + wpart[3];

  if (blockIdx.x == 0 && tid == 0) row_ptr[N] = E;

  int base = blockIdx.x * SCAN_BLK + tid * 8;
  int v[8];
  int sl = 0;
  if (base < N) {
#pragma unroll
    for (int j = 0; j < 8; ++j) { v[j] = counts[base + j]; sl += v[j]; }
  } else {
#pragma unroll
    for (int j = 0; j < 8; ++j) v[j] = 0;
  }
  int x = sl;
#pragma unroll
  for (int d = 1; d < 64; d <<= 1) {
    int y = __shfl_up(x, d, 64);
    if (lane >= d) x += y;
  }
  if (lane == 63) wsum[wv] = x;
  __syncthreads();
  int woff = 0;
  for (int w = 0; w < wv; ++w) woff += wsum[w];
  int run = blk_off + woff + (x - sl);
  if (base < N) {
#pragma unroll
    for (int j = 0; j < 8; ++j) {
      row_ptr[base + j] = run;
      cursor[base + j] = run;
      run += v[j];
    }
  }
}

// ---------------- work_a: scatter edges || pack x to bf16 ----------------
// Blocks [0, cntB): scatter into packed 8B {col,val} CSR records (needs cursor from scan).
// Blocks [cntB, cntB+6250): stream-pack x (f32 -> bf16), 8 elems/thread. Independent work,
// one launch; the streaming pack hides the scatter's atomic latency.
__global__ __launch_bounds__(256) void work_a_kernel(const int* __restrict__ rows,
                                                     const int* __restrict__ cols,
                                                     const float* __restrict__ vals,
                                                     int* __restrict__ cursor,
                                                     uintx2* __restrict__ colval, int E, int cntB,
                                                     const float* __restrict__ x,
                                                     unsigned short* __restrict__ xp) {
  int b = blockIdx.x;
  if (b < cntB) {
    int e = b * 256 + threadIdx.x;
    if (e >= E) return;
    int r = rows[e];
    int p = atomicAdd(&cursor[r], 1);
    uintx2 cv;
    cv[0] = (unsigned)cols[e];
    cv[1] = __float_as_uint(vals[e]);
    colval[p] = cv;
  } else {
    int idx = (b - cntB) * 256 + threadIdx.x;      // exactly N*256/8 threads
    size_t base = (size_t)idx * 8;
    floatx4 f0 = *(const floatx4*)(x + base);
    floatx4 f1 = *(const floatx4*)(x + base + 4);
    short8 o;
#pragma unroll
    for (int j = 0; j < 4; ++j) { o[j] = (short)f2bf(f0[j]); o[4 + j] = (short)f2bf(f1[j]); }
    *(short8*)(xp + base) = o;
  }
}

// ---------------- fused layer: Ax = spmm(A, src) -> LDS -> dual GEMM -> epilogue ----------------
// Uses spmm(A, X) @ W == (A @ X) @ W: gather the NARROW bf16 src rows (512B/edge instead of
// the old 1KB SG-pair rows), accumulate Ax in f32, then dual MFMA GEMM against packed W/G.
// Phase A: wave wid owns rows wid*4..+3. Edge-PAIRED gather: lanes 0-31 = edge e (16B/lane,
// 8 dims), lanes 32-63 = edge e+1; masked-clamped 8-edge unroll keeps 4x16B/lane in flight;
// 8-shuffle cross-half reduce at row end. Phase B: 16x256 @ 256x(TILES*64) dual GEMM.

// fused1: src = xp, epilogue h = relu(sig(G)*S) -> hp bf16 [N][256]
__global__ __launch_bounds__(256) void fused1_kernel(const int* __restrict__ row_ptr,
                                                     const uintx2* __restrict__ colval,
                                                     const unsigned short* __restrict__ xp,
                                                     const unsigned short* __restrict__ Wp,
                                                     const unsigned short* __restrict__ Gp,
                                                     unsigned short* __restrict__ hp) {
  __shared__ short hlds[16 * LDS_STRIDE];
  int lane = threadIdx.x & 63;
  int wid = threadIdx.x >> 6;
  int half = lane >> 5, li = lane & 31;
  int r0 = blockIdx.x * 16;

  // ---- phase A: paired-edge gather of Ax (4 rows/wave) ----
  for (int rl = 0; rl < 4; ++rl) {
    int lrow = wid * 4 + rl;
    int r = r0 + lrow;
    int e0 = row_ptr[r], e1 = row_ptr[r + 1];
    float a[8];
#pragma unroll
    for (int q = 0; q < 8; ++q) a[q] = 0.f;
    for (int eb = e0; eb < e1; eb += 8) {
      uintx2 cv[4];
      float vm[4];
#pragma unroll
      for (int k = 0; k < 4; ++k) {
        int ee = eb + 2 * k + half;
        bool ok = ee < e1;
        cv[k] = colval[ok ? ee : e1 - 1];
        vm[k] = ok ? __uint_as_float(cv[k][1]) : 0.f;
      }
#pragma unroll
      for (int k = 0; k < 4; ++k) {
        uintx4 p = ((const uintx4*)(xp + (size_t)cv[k][0] * 256))[li];
        float v = vm[k];
#pragma unroll
        for (int q = 0; q < 4; ++q) {
          a[2 * q]     += __uint_as_float(p[q] << 16) * v;
          a[2 * q + 1] += __uint_as_float(p[q] & 0xffff0000u) * v;
        }
      }
    }
#pragma unroll
    for (int q = 0; q < 8; ++q) a[q] += __shfl(a[q], lane ^ 32, 64);
    if (half == 0) {
      ushortx8 o;
#pragma unroll
      for (int q = 0; q < 8; ++q) o[q] = f2bf(a[q]);
      *(ushortx8*)(&hlds[lrow * LDS_STRIDE + li * 8]) = o;
    }
  }
  __syncthreads();

  // ---- phase B: 16x256 @ 256x256 dual GEMM, relu(sig*S) epilogue ----
  constexpr int K = 256;
  int quad = lane >> 4, lr = lane & 15;
  int t0 = wid * 4;
  const short* Wb[4];
  const short* Gb[4];
#pragma unroll
  for (int t = 0; t < 4; ++t) {
    size_t boff = (size_t)(t0 + t) * 16 * K + (size_t)lr * K + quad * 8;
    Wb[t] = (const short*)Wp + boff;
    Gb[t] = (const short*)Gp + boff;
  }
  const short* Abase = &hlds[lr * LDS_STRIDE + quad * 8];

  floatx4 zero = {0.f, 0.f, 0.f, 0.f};
  floatx4 accS[4] = {zero, zero, zero, zero}, accG[4] = {zero, zero, zero, zero};
#pragma unroll
  for (int kc = 0; kc < 8; ++kc) {
    short8 av = *(const short8*)(Abase + kc * 32);
#pragma unroll
    for (int t = 0; t < 4; ++t) {
      short8 bw = *(const short8*)(Wb[t] + kc * 32);
      short8 bg = *(const short8*)(Gb[t] + kc * 32);
      accS[t] = __builtin_amdgcn_mfma_f32_16x16x32_bf16(av, bw, accS[t], 0, 0, 0);
      accG[t] = __builtin_amdgcn_mfma_f32_16x16x32_bf16(av, bg, accG[t], 0, 0, 0);
    }
  }
#pragma unroll
  for (int t = 0; t < 4; ++t)
#pragma unroll
    for (int gg = 0; gg < 4; ++gg) {
      int row = r0 + quad * 4 + gg;
      float h = sigmoidf(accG[t][gg]) * accS[t][gg];
      h = fmaxf(h, 0.f);
      hp[(size_t)row * 256 + (t0 + t) * 16 + lr] = f2bf(h);
    }
}

// fused2: src = hp, epilogue out = sig(G)*S (f32) [N][128]
__global__ __launch_bounds__(256) void fused2_kernel(const int* __restrict__ row_ptr,
                                                     const uintx2* __restrict__ colval,
                                                     const unsigned short* __restrict__ hp,
                                                     const unsigned short* __restrict__ Wp,
                                                     const unsigned short* __restrict__ Gp,
                                                     float* __restrict__ out) {
  __shared__ short hlds[16 * LDS_STRIDE];
  int lane = threadIdx.x & 63;
  int wid = threadIdx.x >> 6;
  int half = lane >> 5, li = lane & 31;
  int r0 = blockIdx.x * 16;

  // ---- phase A: paired-edge gather of Ah (4 rows/wave) ----
  for (int rl = 0; rl < 4; ++rl) {
    int lrow = wid * 4 + rl;
    int r = r0 + lrow;
    int e0 = row_ptr[r], e1 = row_ptr[r + 1];
    float a[8];
#pragma unroll
    for (int q = 0; q < 8; ++q) a[q] = 0.f;
    for (int eb = e0; eb < e1; eb += 8) {
      uintx2 cv[4];
      float vm[4];
#pragma unroll
      for (int k = 0; k < 4; ++k) {
        int ee = eb + 2 * k + half;
        bool ok = ee < e1;
        cv[k] = colval[ok ? ee : e1 - 1];
        vm[k] = ok ? __uint_as_float(cv[k][1]) : 0.f;
      }
#pragma unroll
      for (int k = 0; k < 4; ++k) {
        uintx4 p = ((const uintx4*)(hp + (size_t)cv[k][0] * 256))[li];
        float v = vm[k];
#pragma unroll
        for (int q = 0; q < 4; ++q) {
          a[2 * q]     += __uint_as_float(p[q] << 16) * v;
          a[2 * q + 1] += __uint_as_float(p[q] & 0xffff0000u) * v;
        }
      }
    }
#pragma unroll
    for (int q = 0; q < 8; ++q) a[q] += __shfl(a[q], lane ^ 32, 64);
    if (half == 0) {
      ushortx8 o;
#pragma unroll
      for (int q = 0; q < 8; ++q) o[q] = f2bf(a[q]);
      *(ushortx8*)(&hlds[lrow * LDS_STRIDE + li * 8]) = o;
    }
  }
  __syncthreads();

  // ---- phase B: 16x256 @ 256x128 dual GEMM, sig(G)*S epilogue (f32 out) ----
  constexpr int K = 256;
  int quad = lane >> 4, lr = lane & 15;
  int t0 = wid * 2;
  const short* Wb[2];
  const short* Gb[2];
#pragma unroll
  for (int t = 0; t < 2; ++t) {
    size_t boff = (size_t)(t0 + t) * 16 * K + (size_t)lr * K + quad * 8;
    Wb[t] = (const short*)Wp + boff;
    Gb[t] = (const short*)Gp + boff;
  }
  const short* Abase = &hlds[lr * LDS_STRIDE + quad * 8];

  floatx4 zero = {0.f, 0.f, 0.f, 0.f};
  floatx4 accS[2] = {zero, zero}, accG[2] = {zero, zero};
#pragma unroll
  for (int kc = 0; kc < 8; ++kc) {
    short8 av = *(const short8*)(Abase + kc * 32);
#pragma unroll
    for (int t = 0; t < 2; ++t) {
      short8 bw = *(const short8*)(Wb[t] + kc * 32);
      short8 bg = *(const short8*)(Gb[t] + kc * 32);
      accS[t] = __builtin_amdgcn_mfma_f32_16x16x32_bf16(av, bw, accS[t], 0, 0, 0);
      accG[t] = __builtin_amdgcn_mfma_f32_16x16x32_bf16(av, bg, accG[t], 0, 0, 0);
    }
  }
#pragma unroll
  for (int t = 0; t < 2; ++t)
#pragma unroll
    for (int gg = 0; gg < 4; ++gg) {
      int row = r0 + quad * 4 + gg;
      out[(size_t)row * 128 + (t0 + t) * 16 + lr] = sigmoidf(accG[t][gg]) * accS[t][gg];
    }
}

// ---------------- launch ----------------

extern "C" void kernel_launch(void* const* d_in, const int* in_sizes, int n_in,
                              void* d_out, int out_size, void* d_ws, size_t ws_size,
                              hipStream_t stream) {
  const float* x    = (const float*)d_in[0];
  const int*   rows = (const int*)d_in[1];
  const int*   cols = (const int*)d_in[2];
  const float* vals = (const float*)d_in[3];
  const float* W1   = (const float*)d_in[4];
  const float* G1   = (const float*)d_in[5];
  const float* W2   = (const float*)d_in[6];
  const float* G2   = (const float*)d_in[7];

  const int N = N_NODES, E = N_EDGES;
  char* ws = (char*)d_ws;
  size_t off = 0;
  auto alloc = [&](size_t bytes) -> char* {
    off = (off + 255) & ~(size_t)255;
    char* p = ws + off;
    off += bytes;
    return p;
  };
  int*   counts  = (int*)alloc((size_t)N * 4);
  int*   row_ptr = (int*)alloc((size_t)(N + 1) * 4);
  int*   cursor  = (int*)alloc((size_t)N * 4);
  uintx2* colval = (uintx2*)alloc((size_t)E * 8);
  unsigned short* Wp1 = (unsigned short*)alloc(256 * 256 * 2);
  unsigned short* Gp1 = (unsigned short*)alloc(256 * 256 * 2);
  unsigned short* Wp2 = (unsigned short*)alloc(256 * 128 * 2);
  unsigned short* Gp2 = (unsigned short*)alloc(256 * 128 * 2);
  unsigned short* xp  = (unsigned short*)alloc((size_t)N * 256 * 2);  // bf16 x
  unsigned short* hp  = (unsigned short*)alloc((size_t)N * 256 * 2);  // bf16 h

  (void)hipMemsetAsync(counts, 0, (size_t)N * 4, stream);

  int cntB = (E + 255) / 256;           // 3125
  prep_kernel<<<cntB + 768, 256, 0, stream>>>(rows, counts, E, cntB,
                                              W1, G1, W2, G2, Wp1, Gp1, Wp2, Gp2);

  int scanB = (N + SCAN_BLK - 1) / SCAN_BLK;   // 25
  scan_kernel<<<scanB, 256, 0, stream>>>(counts, row_ptr, cursor, N, E);

  // scatter || x-pack
  int packB = (N * 256 / 8) / 256;      // 6250
  work_a_kernel<<<cntB + packB, 256, 0, stream>>>(rows, cols, vals, cursor, colval, E, cntB, x, xp);

  // layer 1: (A @ x) @ {W1,G1}, relu(sig*S) -> hp
  fused1_kernel<<<N / 16, 256, 0, stream>>>(row_ptr, colval, xp, Wp1, Gp1, hp);

  // layer 2: (A @ h) @ {W2,G2}, sig*S -> out
  fused2_kernel<<<N / 16, 256, 0, stream>>>(row_ptr, colval, hp, Wp2, Gp2, (float*)d_out);
}

// Round 3
// 410.564 us; speedup vs baseline: 1.0688x; 1.0655x over previous
//
#include <hip/hip_runtime.h>
#include <math.h>

#define N_NODES 50000
#define N_EDGES 800000
#define SCAN_BLK 2048   // elements per scan block (256 threads x 8)
#define LDS_STRIDE 264  // 256 shorts + 8 pad (bank spread)

using short8  = __attribute__((ext_vector_type(8))) short;
using floatx4 = __attribute__((ext_vector_type(4))) float;
using ushortx8 = __attribute__((ext_vector_type(8))) unsigned short;
using uintx4  = __attribute__((ext_vector_type(4))) unsigned;
using uintx2  = __attribute__((ext_vector_type(2))) unsigned;

__device__ inline unsigned short f2bf(float f) {
  unsigned u = __float_as_uint(f);
  u += 0x7fff + ((u >> 16) & 1);   // round-to-nearest-even
  return (unsigned short)(u >> 16);
}

__device__ inline float sigmoidf(float x) { return 1.0f / (1.0f + __expf(-x)); }

// ---------------- prep: edge count + weight pack ----------------
__global__ void prep_kernel(const int* __restrict__ rows, int* __restrict__ counts, int E, int cntB,
                            const float* __restrict__ W1, const float* __restrict__ G1,
                            const float* __restrict__ W2, const float* __restrict__ G2,
                            unsigned short* __restrict__ Wp1, unsigned short* __restrict__ Gp1,
                            unsigned short* __restrict__ Wp2, unsigned short* __restrict__ Gp2) {
  int b = blockIdx.x;
  if (b < cntB) {
    int e = b * 256 + threadIdx.x;
    if (e < E) atomicAdd(&counts[rows[e]], 1);
  } else {
    int idx = (b - cntB) * 256 + threadIdx.x;
    if (idx < 65536) {
      int m = idx >> 8, k = idx & 255;
      Wp1[idx] = f2bf(W1[k * 256 + m]);
    } else if (idx < 131072) {
      int t = idx - 65536; int m = t >> 8, k = t & 255;
      Gp1[t] = f2bf(G1[k * 256 + m]);
    } else if (idx < 163840) {
      int t = idx - 131072; int m = t >> 8, k = t & 255;
      Wp2[t] = f2bf(W2[k * 128 + m]);
    } else {
      int t = idx - 163840; int m = t >> 8, k = t & 255;
      Gp2[t] = f2bf(G2[k * 128 + m]);
    }
  }
}

// ---------------- single-kernel exclusive scan ----------------
__global__ void scan_kernel(const int* __restrict__ counts, int* __restrict__ row_ptr,
                            int* __restrict__ cursor, int N, int E) {
  int tid = threadIdx.x, lane = tid & 63, wv = tid >> 6;
  __shared__ int wpart[4], wsum[4];

  int limit4 = (blockIdx.x * SCAN_BLK) >> 2;
  const int4* c4 = (const int4*)counts;
  int s = 0;
  for (int i = tid; i < limit4; i += 256) {
    int4 v = c4[i];
    s += v.x + v.y + v.z + v.w;
  }
#pragma unroll
  for (int d = 32; d > 0; d >>= 1) s += __shfl_down(s, d, 64);
  if (lane == 0) wpart[wv] = s;
  __syncthreads();
  int blk_off = wpart[0] + wpart[1] + wpart[2] + wpart[3];

  if (blockIdx.x == 0 && tid == 0) row_ptr[N] = E;

  int base = blockIdx.x * SCAN_BLK + tid * 8;
  int v[8];
  int sl = 0;
  if (base < N) {
#pragma unroll
    for (int j = 0; j < 8; ++j) { v[j] = counts[base + j]; sl += v[j]; }
  } else {
#pragma unroll
    for (int j = 0; j < 8; ++j) v[j] = 0;
  }
  int x = sl;
#pragma unroll
  for (int d = 1; d < 64; d <<= 1) {
    int y = __shfl_up(x, d, 64);
    if (lane >= d) x += y;
  }
  if (lane == 63) wsum[wv] = x;
  __syncthreads();
  int woff = 0;
  for (int w = 0; w < wv; ++w) woff += wsum[w];
  int run = blk_off + woff + (x - sl);
  if (base < N) {
#pragma unroll
    for (int j = 0; j < 8; ++j) {
      row_ptr[base + j] = run;
      cursor[base + j] = run;
      run += v[j];
    }
  }
}

// ---------------- work_a: scatter edges || pack x to bf16 ----------------
__global__ __launch_bounds__(256) void work_a_kernel(const int* __restrict__ rows,
                                                     const int* __restrict__ cols,
                                                     const float* __restrict__ vals,
                                                     int* __restrict__ cursor,
                                                     uintx2* __restrict__ colval, int E, int cntB,
                                                     const float* __restrict__ x,
                                                     unsigned short* __restrict__ xp) {
  int b = blockIdx.x;
  if (b < cntB) {
    int e = b * 256 + threadIdx.x;
    if (e >= E) return;
    int r = rows[e];
    int p = atomicAdd(&cursor[r], 1);
    uintx2 cv;
    cv[0] = (unsigned)cols[e];
    cv[1] = __float_as_uint(vals[e]);
    colval[p] = cv;
  } else {
    int idx = (b - cntB) * 256 + threadIdx.x;      // exactly N*256/8 threads
    size_t base = (size_t)idx * 8;
    floatx4 f0 = *(const floatx4*)(x + base);
    floatx4 f1 = *(const floatx4*)(x + base + 4);
    short8 o;
#pragma unroll
    for (int j = 0; j < 4; ++j) { o[j] = (short)f2bf(f0[j]); o[4 + j] = (short)f2bf(f1[j]); }
    *(short8*)(xp + base) = o;
  }
}

// ---------------- phase A core: row-per-half-wave gather ----------------
// Each half-wave (32 lanes x 16B = 512B) owns ONE full src row. Lane-parallel colval
// prefetch (1 load = 32 edge records), per-edge {col,val} via __shfl broadcast (no VMEM,
// no address dependency). Gathers issued in 4-deep groups, explicitly double-buffered:
// group i+1 is in flight before group i is consumed. All 16 rows of the block gather
// IN PARALLEL (vs 4-serial-per-wave before) -> 8x shorter serial chain per row.
__device__ inline void gather_row(const uintx2* __restrict__ colval,
                                  const unsigned short* __restrict__ src,
                                  int e0, int n, int half, int li, float a[8]) {
#pragma unroll
  for (int q = 0; q < 8; ++q) a[q] = 0.f;
  int done = 0;
  while (done < n) {
    int win = n - done;
    if (win > 32) win = 32;
    uintx2 cvl = colval[e0 + done + (li < win ? li : win - 1)];

    uintx4 p[4];
    float v[4];
    int m = 0;
    // prologue: issue group 0
#pragma unroll
    for (int k = 0; k < 4; ++k) {
      int mm = k;
      bool ok = mm < win;
      int srcl = (half << 5) | (ok ? mm : 0);
      unsigned col = (unsigned)__shfl((int)cvl[0], srcl, 64);
      v[k] = ok ? __uint_as_float((unsigned)__shfl((int)cvl[1], srcl, 64)) : 0.f;
      p[k] = ((const uintx4*)(src + (size_t)col * 256))[li];
    }
    for (m = 4; m < win; m += 4) {
      uintx4 p2[4];
      float v2[4];
#pragma unroll
      for (int k = 0; k < 4; ++k) {
        int mm = m + k;
        bool ok = mm < win;
        int srcl = (half << 5) | (ok ? mm : 0);
        unsigned col = (unsigned)__shfl((int)cvl[0], srcl, 64);
        v2[k] = ok ? __uint_as_float((unsigned)__shfl((int)cvl[1], srcl, 64)) : 0.f;
        p2[k] = ((const uintx4*)(src + (size_t)col * 256))[li];
      }
#pragma unroll
      for (int k = 0; k < 4; ++k) {
        float vv = v[k];
#pragma unroll
        for (int q = 0; q < 4; ++q) {
          a[2 * q]     += __uint_as_float(p[k][q] << 16) * vv;
          a[2 * q + 1] += __uint_as_float(p[k][q] & 0xffff0000u) * vv;
        }
      }
#pragma unroll
      for (int k = 0; k < 4; ++k) { p[k] = p2[k]; v[k] = v2[k]; }
    }
    // epilogue: consume last group
#pragma unroll
    for (int k = 0; k < 4; ++k) {
      float vv = v[k];
#pragma unroll
      for (int q = 0; q < 4; ++q) {
        a[2 * q]     += __uint_as_float(p[k][q] << 16) * vv;
        a[2 * q + 1] += __uint_as_float(p[k][q] & 0xffff0000u) * vv;
      }
    }
    done += win;
  }
}

// ---------------- fused1: (A @ x) @ {W1,G1}, relu(sig*S) -> hp bf16 [N][256] ----------------
// 512 threads = 8 waves = 16 half-waves = 16 rows gathered in parallel, then
// 16x256 @ 256x256 dual GEMM (2 N-tiles per wave).
__global__ __launch_bounds__(512) void fused1_kernel(const int* __restrict__ row_ptr,
                                                     const uintx2* __restrict__ colval,
                                                     const unsigned short* __restrict__ xp,
                                                     const unsigned short* __restrict__ Wp,
                                                     const unsigned short* __restrict__ Gp,
                                                     unsigned short* __restrict__ hp) {
  __shared__ short hlds[16 * LDS_STRIDE];
  int lane = threadIdx.x & 63;
  int wid = threadIdx.x >> 6;
  int half = lane >> 5, li = lane & 31;
  int r0 = blockIdx.x * 16;
  int lrow = wid * 2 + half;
  int r = r0 + lrow;

  // ---- phase A ----
  int e0 = row_ptr[r], e1 = row_ptr[r + 1];
  float a[8];
  gather_row(colval, xp, e0, e1 - e0, half, li, a);
  ushortx8 o;
#pragma unroll
  for (int q = 0; q < 8; ++q) o[q] = f2bf(a[q]);
  *(ushortx8*)(&hlds[lrow * LDS_STRIDE + li * 8]) = o;
  __syncthreads();

  // ---- phase B: 16x256 @ 256x256 dual GEMM, relu(sig*S) epilogue ----
  constexpr int K = 256;
  int quad = lane >> 4, lr = lane & 15;
  int t0 = wid * 2;
  const short* Wb[2];
  const short* Gb[2];
#pragma unroll
  for (int t = 0; t < 2; ++t) {
    size_t boff = (size_t)(t0 + t) * 16 * K + (size_t)lr * K + quad * 8;
    Wb[t] = (const short*)Wp + boff;
    Gb[t] = (const short*)Gp + boff;
  }
  const short* Abase = &hlds[lr * LDS_STRIDE + quad * 8];

  floatx4 zero = {0.f, 0.f, 0.f, 0.f};
  floatx4 accS[2] = {zero, zero}, accG[2] = {zero, zero};
#pragma unroll
  for (int kc = 0; kc < 8; ++kc) {
    short8 av = *(const short8*)(Abase + kc * 32);
#pragma unroll
    for (int t = 0; t < 2; ++t) {
      short8 bw = *(const short8*)(Wb[t] + kc * 32);
      short8 bg = *(const short8*)(Gb[t] + kc * 32);
      accS[t] = __builtin_amdgcn_mfma_f32_16x16x32_bf16(av, bw, accS[t], 0, 0, 0);
      accG[t] = __builtin_amdgcn_mfma_f32_16x16x32_bf16(av, bg, accG[t], 0, 0, 0);
    }
  }
#pragma unroll
  for (int t = 0; t < 2; ++t)
#pragma unroll
    for (int gg = 0; gg < 4; ++gg) {
      int row = r0 + quad * 4 + gg;
      float h = sigmoidf(accG[t][gg]) * accS[t][gg];
      h = fmaxf(h, 0.f);
      hp[(size_t)row * 256 + (t0 + t) * 16 + lr] = f2bf(h);
    }
}

// ---------------- fused2: (A @ h) @ {W2,G2}, sig*S -> out f32 [N][128] ----------------
__global__ __launch_bounds__(512) void fused2_kernel(const int* __restrict__ row_ptr,
                                                     const uintx2* __restrict__ colval,
                                                     const unsigned short* __restrict__ hp,
                                                     const unsigned short* __restrict__ Wp,
                                                     const unsigned short* __restrict__ Gp,
                                                     float* __restrict__ out) {
  __shared__ short hlds[16 * LDS_STRIDE];
  int lane = threadIdx.x & 63;
  int wid = threadIdx.x >> 6;
  int half = lane >> 5, li = lane & 31;
  int r0 = blockIdx.x * 16;
  int lrow = wid * 2 + half;
  int r = r0 + lrow;

  // ---- phase A ----
  int e0 = row_ptr[r], e1 = row_ptr[r + 1];
  float a[8];
  gather_row(colval, hp, e0, e1 - e0, half, li, a);
  ushortx8 o;
#pragma unroll
  for (int q = 0; q < 8; ++q) o[q] = f2bf(a[q]);
  *(ushortx8*)(&hlds[lrow * LDS_STRIDE + li * 8]) = o;
  __syncthreads();

  // ---- phase B: 16x256 @ 256x128 dual GEMM, sig(G)*S epilogue (f32 out) ----
  constexpr int K = 256;
  int quad = lane >> 4, lr = lane & 15;
  int t = wid;  // 8 waves x 1 tile = 128 cols
  const short* Wb = (const short*)Wp + (size_t)t * 16 * K + (size_t)lr * K + quad * 8;
  const short* Gb = (const short*)Gp + (size_t)t * 16 * K + (size_t)lr * K + quad * 8;
  const short* Abase = &hlds[lr * LDS_STRIDE + quad * 8];

  floatx4 zero = {0.f, 0.f, 0.f, 0.f};
  floatx4 accS = zero, accG = zero;
#pragma unroll
  for (int kc = 0; kc < 8; ++kc) {
    short8 av = *(const short8*)(Abase + kc * 32);
    short8 bw = *(const short8*)(Wb + kc * 32);
    short8 bg = *(const short8*)(Gb + kc * 32);
    accS = __builtin_amdgcn_mfma_f32_16x16x32_bf16(av, bw, accS, 0, 0, 0);
    accG = __builtin_amdgcn_mfma_f32_16x16x32_bf16(av, bg, accG, 0, 0, 0);
  }
#pragma unroll
  for (int gg = 0; gg < 4; ++gg) {
    int row = r0 + quad * 4 + gg;
    out[(size_t)row * 128 + t * 16 + lr] = sigmoidf(accG[gg]) * accS[gg];
  }
}

// ---------------- launch ----------------

extern "C" void kernel_launch(void* const* d_in, const int* in_sizes, int n_in,
                              void* d_out, int out_size, void* d_ws, size_t ws_size,
                              hipStream_t stream) {
  const float* x    = (const float*)d_in[0];
  const int*   rows = (const int*)d_in[1];
  const int*   cols = (const int*)d_in[2];
  const float* vals = (const float*)d_in[3];
  const float* W1   = (const float*)d_in[4];
  const float* G1   = (const float*)d_in[5];
  const float* W2   = (const float*)d_in[6];
  const float* G2   = (const float*)d_in[7];

  const int N = N_NODES, E = N_EDGES;
  char* ws = (char*)d_ws;
  size_t off = 0;
  auto alloc = [&](size_t bytes) -> char* {
    off = (off + 255) & ~(size_t)255;
    char* p = ws + off;
    off += bytes;
    return p;
  };
  int*   counts  = (int*)alloc((size_t)N * 4);
  int*   row_ptr = (int*)alloc((size_t)(N + 1) * 4);
  int*   cursor  = (int*)alloc((size_t)N * 4);
  uintx2* colval = (uintx2*)alloc((size_t)E * 8);
  unsigned short* Wp1 = (unsigned short*)alloc(256 * 256 * 2);
  unsigned short* Gp1 = (unsigned short*)alloc(256 * 256 * 2);
  unsigned short* Wp2 = (unsigned short*)alloc(256 * 128 * 2);
  unsigned short* Gp2 = (unsigned short*)alloc(256 * 128 * 2);
  unsigned short* xp  = (unsigned short*)alloc((size_t)N * 256 * 2);  // bf16 x
  unsigned short* hp  = (unsigned short*)alloc((size_t)N * 256 * 2);  // bf16 h

  (void)hipMemsetAsync(counts, 0, (size_t)N * 4, stream);

  int cntB = (E + 255) / 256;           // 3125
  prep_kernel<<<cntB + 768, 256, 0, stream>>>(rows, counts, E, cntB,
                                              W1, G1, W2, G2, Wp1, Gp1, Wp2, Gp2);

  int scanB = (N + SCAN_BLK - 1) / SCAN_BLK;   // 25
  scan_kernel<<<scanB, 256, 0, stream>>>(counts, row_ptr, cursor, N, E);

  // scatter || x-pack
  int packB = (N * 256 / 8) / 256;      // 6250
  work_a_kernel<<<cntB + packB, 256, 0, stream>>>(rows, cols, vals, cursor, colval, E, cntB, x, xp);

  // layer 1: (A @ x) @ {W1,G1}, relu(sig*S) -> hp
  fused1_kernel<<<N / 16, 512, 0, stream>>>(row_ptr, colval, xp, Wp1, Gp1, hp);

  // layer 2: (A @ h) @ {W2,G2}, sig*S -> out
  fused2_kernel<<<N / 16, 512, 0, stream>>>(row_ptr, colval, hp, Wp2, Gp2, (float*)d_out);
}